// Round 6
// baseline (292.388 us; speedup 1.0000x reference)
//
#include <hip/hip_runtime.h>
#include <math.h>

// ---------------------------------------------------------------------------
// EncoderGPECls: kNN(16) -> PCA curvature blend -> adaptive GPE embeddings
// xyz: [8,4096,3] f32  ->  out: [8,4096,128] f32
//
// R18 = R17 knn at EXACT 4 blocks/CU + lean out path.
//   R12-R17 evidence: true VALU issue pinned ~28% across 1.7-6 waves/SIMD;
//   knn gains from occupancy are small but real (213->206). Non-knn time
//   (~75us) has concrete waste: out_kernel's 16384 blocks each redo the
//   512-float csum prefix; knn's 3/CU grid has a ragged tail.
//   Changes:
//   (a) knn arena -> 8192B (sbuf 16 LDS slots + 17th survivor in VGPR,
//       identical SCAP=17 clamp semantics; pub -> 2 regions, round 1 split
//       into two barrier phases -- R14-proven sequence). LDS 40960B x 4 =
//       exactly 160KiB; grid 1024 = 4x256 -> all blocks co-resident.
//       __launch_bounds__(512,8) (R17 measured 40 VGPR; <=64 safe).
//   (b) merge_kernel csum via 8 atomicAdd floats (zeroed in prep);
//       out_kernel prefix ~30 instr, body float4-vectorized, 4096 blocks.
//   (c) 4 dispatches: prep, knn, merge, out.
//   Falsification pre-commit: knn >=200us AND occupancy >=80% kills the
//   TLP/latency theory -> next round streams candidates via s_load/SGPR.
//
// ws float layout:
//   [0, 32768)            curv per point
//   [32768, 131072)       rasig2 (3 SoA planes of 32768)
//   [131072, 131080)      curv atomic sums [b] (8 floats, zeroed by prep)
//   [131584, 131680)      per-batch raw sums as 48 DOUBLES
//   [131680, 262752)      repacked points: 8*4096 float4 (-2x,-2y,-2z,|c|^2)
// d_out scratch (before out_kernel): keys[(b*64+chunk)*2+half][17][64] u64
// ---------------------------------------------------------------------------

#define NPTS 4096
#define KNN 17          // 16 neighbors + self (self contributes zero to sums)
#define BLKT 512        // 8 waves; 64 queries per block (1 per lane)
#define QPB 64
#define HALFN 2048      // points per half-cloud tile (32 KB)
#define PART 256        // candidates per wave partition
#define SCAP 17         // survivor capacity per lane (16 LDS + 1 VGPR)

#define WS_CURV  0
#define WS_RAS2  32768
#define WS_CSUM8 131072
#define WS_STAT  131584
#define WS_PTS   131680

typedef unsigned long long ull;
#define SENT 0xFFFFFFFFFFFFFFFFULL

// THE single d2' definition: explicit fmaf chain, identical IEEE ops at every
// call site. c = (-2cx,-2cy,-2cz,|c|^2), q = original coords.
// d2'(c,q) = |c|^2 - 2 c.q = |c-q|^2 - |q|^2 (per-query constant offset ->
// identical ordering; can be negative). Self always ranks first.
__device__ __forceinline__ float d2p(float4 c, float qx, float qy, float qz) {
    return __builtin_fmaf(c.x, qx, __builtin_fmaf(c.y, qy,
           __builtin_fmaf(c.z, qz, c.w)));
}

// order-preserving u32 encoding of a (possibly negative) float
__device__ __forceinline__ unsigned encf(float f) {
    unsigned u = __float_as_uint(f);
    return u ^ (unsigned)(((int)u >> 31) | 0x80000000u);
}

// predicated replace-max insert of packed (enc(d2')<<32|idx) key
__device__ __forceinline__ void insertp(ull v, bool ins, ull (&md)[KNN],
                                        ull& maxv, int& maxp) {
#pragma unroll
    for (int k = 0; k < KNN; k++) {
        bool sel = ins && (k == maxp);
        md[k] = sel ? v : md[k];
    }
    maxv = md[0]; maxp = 0;
#pragma unroll
    for (int k = 1; k < KNN; k++) {
        bool g = md[k] > maxv;
        maxv = g ? md[k] : maxv;
        maxp = g ? k : maxp;
    }
}

// ---------------- 3x3 symmetric eigensolve (double, trig method) -----------
__device__ __forceinline__ float curv_from_cov(float c00, float c01, float c02,
                                               float c11, float c12, float c22) {
    double a00 = c00, a01 = c01, a02 = c02, a11 = c11, a12 = c12, a22 = c22;
    double tr = a00 + a11 + a22;
    double q  = tr * (1.0 / 3.0);
    double b00 = a00 - q, b11 = a11 - q, b22 = a22 - q;
    double p2 = b00 * b00 + b11 * b11 + b22 * b22
              + 2.0 * (a01 * a01 + a02 * a02 + a12 * a12);
    double lmin;
    if (p2 < 1e-60) {
        lmin = q;
    } else {
        double p  = sqrt(p2 * (1.0 / 6.0));
        double ip = 1.0 / p;
        double m00 = b00 * ip, m11 = b11 * ip, m22 = b22 * ip;
        double m01 = a01 * ip, m02 = a02 * ip, m12 = a12 * ip;
        double det = m00 * (m11 * m22 - m12 * m12)
                   - m01 * (m01 * m22 - m12 * m02)
                   + m02 * (m01 * m12 - m11 * m02);
        double r = 0.5 * det;
        r = r > 1.0 ? 1.0 : (r < -1.0 ? -1.0 : r);
        double phi = acos(r) * (1.0 / 3.0);
        lmin = q + 2.0 * p * cos(phi + 2.0943951023931953);
    }
    return (float)(lmin / (tr + 1e-6));
}

// ---------------- repack + per-batch raw stats + csum zero -----------------
__global__ void prep_kernel(const float* __restrict__ xyz,
                            float* __restrict__ ws) {
    __shared__ double dstat[48];
    int b = blockIdx.x;
    int tid = threadIdx.x;
    const float* base = xyz + b * NPTS * 3;
    float4* P4 = (float4*)(ws + WS_PTS) + b * NPTS;
    double sx = 0, sy = 0, sz = 0, qxx = 0, qyy = 0, qzz = 0;
    for (int p = tid; p < NPTS; p += BLKT) {
        float x = base[p * 3], y = base[p * 3 + 1], z = base[p * 3 + 2];
        float w = __builtin_fmaf(z, z, __builtin_fmaf(y, y, x * x));
        P4[p] = make_float4(-2.0f * x, -2.0f * y, -2.0f * z, w);
        sx += (double)x; sy += (double)y; sz += (double)z;
        qxx += (double)x * x; qyy += (double)y * y; qzz += (double)z * z;
    }
    for (int off = 32; off > 0; off >>= 1) {
        sx += __shfl_down(sx, off);  sy += __shfl_down(sy, off);
        sz += __shfl_down(sz, off);  qxx += __shfl_down(qxx, off);
        qyy += __shfl_down(qyy, off); qzz += __shfl_down(qzz, off);
    }
    int wid = tid >> 6;
    if ((tid & 63) == 0) {
        dstat[wid * 6 + 0] = sx;  dstat[wid * 6 + 1] = sy;  dstat[wid * 6 + 2] = sz;
        dstat[wid * 6 + 3] = qxx; dstat[wid * 6 + 4] = qyy; dstat[wid * 6 + 5] = qzz;
    }
    __syncthreads();
    if (tid == 0) {
        double* wd = (double*)(ws + WS_STAT);
        for (int qq = 0; qq < 6; qq++) {
            double a = 0.0;
            for (int w = 0; w < 8; w++) a += dstat[w * 6 + qq];
            wd[b * 6 + qq] = a;
        }
        ws[WS_CSUM8 + b] = 0.0f;      // zero the atomic curv accumulator
    }
}

// ---------------- kNN over one half-cloud: per-(query,half) exact top-17 ---
__global__ __launch_bounds__(BLKT, 8) void knn_kernel(float* __restrict__ ws,
                                                      ull* __restrict__ keys) {
    __shared__ float4 tile[HALFN];               // 32768 B half-cloud
    __shared__ ull aux[1024];                    // 8192 B arena (aliased)
    unsigned char* sbuf = (unsigned char*)aux;   // [16][BLKT] u8 survivors
    unsigned short* pub = (unsigned short*)aux;  // 2 regions x 64x17 u16 idx

    int blk = blockIdx.x;
    int b = blk >> 7;                            // 128 blocks per batch
    int rest = blk & 127;
    int half = rest & 1;
    int chunk = rest >> 1;                       // 64 chunks of 64 queries
    int tid = threadIdx.x;
    const float4* __restrict__ P4g = (const float4*)(ws + WS_PTS) + b * NPTS;
    int hbase = half * HALFN;
    for (int p = tid; p < HALFN; p += BLKT) tile[p] = P4g[hbase + p];
    __syncthreads();

    int wv = tid >> 6;                           // wave id: candidate 1/8th
    int lane = tid & 63;
    int i = chunk * QPB + lane;                  // this lane's query (global)
    float4 qc = P4g[i];                          // query may be in other half
    float qx = -0.5f * qc.x, qy = -0.5f * qc.y, qz = -0.5f * qc.z;  // exact
    int cb = wv * PART;                          // partition base within tile

    // ---- pass 1: branch-free med3 sorted top-17 (values only) -------------
    float md[KNN];
#pragma unroll
    for (int k = 0; k < KNN; k++) md[k] = 3.4e38f;

    float4 cc[4];
#pragma unroll
    for (int u = 0; u < 4; u++) cc[u] = tile[cb + u];
    for (int m = 0; m < PART; m += 4) {
        float4 cu[4];
#pragma unroll
        for (int u = 0; u < 4; u++) cu[u] = cc[u];
        int mn = (m + 4 < PART) ? (m + 4) : 0;   // last prefetch redundant
#pragma unroll
        for (int u = 0; u < 4; u++) cc[u] = tile[cb + mn + u];
#pragma unroll
        for (int u = 0; u < 4; u++) {
            float d2 = d2p(cu[u], qx, qy, qz);
#pragma unroll
            for (int k = KNN - 1; k >= 1; k--)   // descending: reads olds only
                md[k] = __builtin_amdgcn_fmed3f(d2, md[k - 1], md[k]);
            md[0] = fminf(d2, md[0]);
        }
    }
    float tau = md[KNN - 1];   // exact 17th of partition (same chain below)

    // ---- pass 2: survivors (16 LDS slots + 17th in VGPR) ------------------
    int cnt = 0;
    int s17 = 0;
#pragma unroll
    for (int u = 0; u < 4; u++) cc[u] = tile[cb + u];
    for (int m = 0; m < PART; m += 4) {
        float4 cu[4];
#pragma unroll
        for (int u = 0; u < 4; u++) cu[u] = cc[u];
        int mn = (m + 4 < PART) ? (m + 4) : 0;
#pragma unroll
        for (int u = 0; u < 4; u++) cc[u] = tile[cb + mn + u];
#pragma unroll
        for (int u = 0; u < 4; u++) {
            float d2 = d2p(cu[u], qx, qy, qz);
            if (d2 <= tau) {                     // clamp drops latest tie = jax
                if (cnt < 16) sbuf[cnt * BLKT + tid] = (unsigned char)(m + u);
                else if (cnt == 16) s17 = m + u;
                cnt++;
            }
        }
    }

    // ---- drain survivors into the exact u64 top-17 (keys: GLOBAL idx) -----
    ull k17[KNN];
#pragma unroll
    for (int k = 0; k < KNN; k++) k17[k] = SENT;
    ull maxv = SENT; int maxp = 0;
#pragma unroll
    for (int t = 0; t < SCAP; t++) {
        if (__any(t < cnt)) {
            int off = (t < 16) ? (int)sbuf[t * BLKT + tid] : s17;
            float4 c = tile[cb + off];
            int ix = hbase + cb + off;           // global per-batch index
            float d2 = d2p(c, qx, qy, qz);
            ull key = ((ull)encf(d2) << 32) | (unsigned)ix;
            bool ins = (t < cnt) && (key < maxv);
            if (__any(ins)) insertp(key, ins, k17, maxv, maxp);
        }
    }

    // ---- tournament merge: 2 pub regions, round 1 split in two phases -----
    // region r: pub[r*1088 + lane*17 + k]; ix global per-batch; tile ix-hbase
#define PUBL(r) { _Pragma("unroll") \
    for (int k = 0; k < KNN; k++) \
        pub[(r) * 1088 + lane * KNN + k] = (unsigned short)(k17[k] & 0xffffULL); }
#define MERGEL(r) { _Pragma("unroll") \
    for (int k = 0; k < KNN; k++) { \
        int ix = pub[(r) * 1088 + lane * KNN + k]; \
        float4 c = tile[ix - hbase]; \
        float d2 = d2p(c, qx, qy, qz); \
        ull key = ((ull)encf(d2) << 32) | (unsigned)ix; \
        bool ins = key < maxv; \
        if (__any(ins)) insertp(key, ins, k17, maxv, maxp); } }

    __syncthreads();
    if (wv == 1 || wv == 3) PUBL(wv >> 1);           // 1->r0, 3->r1
    __syncthreads();
    if (wv == 0 || wv == 2) MERGEL(wv >> 1);
    __syncthreads();
    if (wv == 5 || wv == 7) PUBL((wv - 4) >> 1);     // 5->r0, 7->r1
    __syncthreads();
    if (wv == 4 || wv == 6) MERGEL((wv - 4) >> 1);
    __syncthreads();
    if (wv == 2 || wv == 6) PUBL(wv >> 2);           // 2->r0, 6->r1
    __syncthreads();
    if (wv == 0 || wv == 4) MERGEL(wv >> 2);
    __syncthreads();
    if (wv == 4) PUBL(0);                            // 4->r0
    __syncthreads();

    // ---- wave 0: final merge; publish (query,half) top-17 u64 keys --------
    if (wv == 0) {
        MERGEL(0);
        ull* ko = keys + (ull)(((b * 64 + chunk) * 2 + half)) * 1088;
#pragma unroll
        for (int k = 0; k < KNN; k++) ko[k * 64 + lane] = k17[k];  // coalesced
    }
#undef PUBL
#undef MERGEL
}

// ---------------- merge halves + moments -> curv, rasig2 -------------------
__global__ void merge_kernel(float* __restrict__ ws,
                             const ull* __restrict__ keys) {
    int W = blockIdx.x * 4 + ((int)threadIdx.x >> 6);   // wave id in [0,512)
    int lane = threadIdx.x & 63;
    int b = W >> 6;                                     // batch
    int q = (W & 63) * QPB + lane;                      // per-batch query idx
    const float4* __restrict__ P4 = (const float4*)(ws + WS_PTS) + b * NPTS;
    float4 qc = P4[q];
    float qx = -0.5f * qc.x, qy = -0.5f * qc.y, qz = -0.5f * qc.z;

    const ull* l0 = keys + (ull)(W * 2) * 1088;         // half 0 list
    ull k17[KNN];
#pragma unroll
    for (int k = 0; k < KNN; k++) k17[k] = l0[k * 64 + lane];
    ull maxv = k17[0]; int maxp = 0;
#pragma unroll
    for (int k = 1; k < KNN; k++) {
        bool g = k17[k] > maxv;
        maxv = g ? k17[k] : maxv;
        maxp = g ? k : maxp;
    }
    const ull* l1 = l0 + 1088;                          // half 1 list
#pragma unroll
    for (int k = 0; k < KNN; k++) {
        ull key = l1[k * 64 + lane];
        bool ins = key < maxv;
        if (__any(ins)) insertp(key, ins, k17, maxv, maxp);
    }

    // ---- moments over the exact global top-17 (incl self: contributes 0) --
    float s1x = 0, s1y = 0, s1z = 0;
    float cxx = 0, cxy = 0, cxz = 0, cyy = 0, cyz = 0, czz = 0;
#pragma unroll
    for (int k = 0; k < KNN; k++) {
        int j = (int)(k17[k] & 0xffffffffULL);
        float4 c = P4[j];                               // L2-resident gather
        float ux = -0.5f * c.x - qx;                    // exact original coords
        float uy = -0.5f * c.y - qy;
        float uz = -0.5f * c.z - qz;
        s1x += ux; s1y += uy; s1z += uz;
        cxx += ux * ux; cxy += ux * uy; cxz += ux * uz;
        cyy += uy * uy; cyz += uy * uz; czz += uz * uz;
    }
    const float i16 = 1.0f / 16.0f, i15 = 1.0f / 15.0f;
    float mx = s1x * i16, my = s1y * i16, mz = s1z * i16;
    float c00 = (cxx - 16.0f * mx * mx) * i15;
    float c01 = (cxy - 16.0f * mx * my) * i15;
    float c02 = (cxz - 16.0f * mx * mz) * i15;
    float c11 = (cyy - 16.0f * my * my) * i15;
    float c12 = (cyz - 16.0f * my * mz) * i15;
    float c22 = (czz - 16.0f * mz * mz) * i15;

    float curv = curv_from_cov(c00, c01, c02, c11, c12, c22);

    float v0 = c00 > 0.0f ? c00 : 0.0f;
    float v1 = c11 > 0.0f ? c11 : 0.0f;
    float v2 = c22 > 0.0f ? c22 : 0.0f;
    float r2x = 1.0f / (0.3f * (1.0f + sqrtf(v0)) + 1e-6f);
    float r2y = 1.0f / (0.3f * (1.0f + sqrtf(v1)) + 1e-6f);
    float r2z = 1.0f / (0.3f * (1.0f + sqrtf(v2)) + 1e-6f);

    int g = b * NPTS + q;
    ws[WS_CURV + g] = curv;
    ws[WS_RAS2 + 0 * 32768 + g] = r2x;
    ws[WS_RAS2 + 1 * 32768 + g] = r2y;
    ws[WS_RAS2 + 2 * 32768 + g] = r2z;

    // per-wave shuffle reduce -> one atomicAdd per wave (8 accumulators)
    float cs = curv;
    for (int off = 32; off > 0; off >>= 1) cs += __shfl_down(cs, off);
    if (lane == 0) atomicAdd(&ws[WS_CSUM8 + b], cs);
}

// ---------------- final embedding (lean prefix, float4 stores) -------------
__global__ void out_kernel(const float* __restrict__ xyz,
                           const float* __restrict__ ws,
                           float* __restrict__ out) {
    __shared__ float sc[3];                      // rasig1, blend, 1-blend
    __shared__ float scm[8];                     // per-batch curv mean
    if (threadIdx.x < 64) {
        // gstd from double stats (24 lanes) -> sigmoid scalars
        float part = 0.0f;
        if (threadIdx.x < 24) {
            const double* st = (const double*)(ws + WS_STAT);
            int bb = threadIdx.x / 3, dd = threadIdx.x % 3;
            double s = st[bb * 6 + dd], ss = st[bb * 6 + 3 + dd];
            double var = (ss - s * s / 4096.0) / 4095.0;
            part = (float)sqrt(var > 0.0 ? var : 0.0);
        }
        float p2 = part;
        for (int off = 32; off > 0; off >>= 1) p2 += __shfl_down(p2, off);
        if (threadIdx.x == 0) {
            float gf = p2 * (1.0f / 24.0f);
            float denom = 0.3f * (1.0f + gf) + 1e-6f;
            float blend = 1.0f / (1.0f + __expf(-(gf - 0.1f) * 10.0f));
            sc[0] = 1.0f / denom;
            sc[1] = blend;
            sc[2] = 1.0f - blend;
        }
        if (threadIdx.x < 8)
            scm[threadIdx.x] = ws[WS_CSUM8 + threadIdx.x] * (1.0f / 4096.0f);
    }
    __syncthreads();

    int q4 = blockIdx.x * 256 + (int)threadIdx.x;     // quad id (4 outputs)
    int j0 = (q4 & 31) << 2;                          // 32 quads per point
    int g  = q4 >> 5;
    int b  = g >> 12;
    float rasig1 = sc[0];
    float blend  = sc[1];
    float blendc = sc[2];
    float curv   = ws[WS_CURV + g];
    float w = 1.0f / (1.0f + __expf(-10.0f * (curv - scm[b])));
    float wc = 1.0f - w;

    float o[4];
#pragma unroll
    for (int e = 0; e < 4; e++) {
        int j = j0 + e;
        int f = (j < 127) ? j : 128;                  // OUT_IDX
        int d = (f >= 86) ? 2 : ((f >= 43) ? 1 : 0);
        int t = f - d * 43;
        float fv = (float)((double)(t + 1) * (2.0 / 44.0) - 1.0);  // FEAT_VAL
        float x = xyz[g * 3 + d];
        float t1 = (x - fv) * rasig1;
        float e1 = blend * __expf(-0.5f * t1 * t1) + blendc * __cosf(t1);
        float t2 = (x - fv) * ws[WS_RAS2 + (d << 15) + g];
        float e2 = __expf(-0.5f * t2 * t2);
        o[e] = w * e1 + wc * e2;
    }
    *(float4*)(out + ((long)q4 << 2)) = make_float4(o[0], o[1], o[2], o[3]);
}

extern "C" void kernel_launch(void* const* d_in, const int* in_sizes, int n_in,
                              void* d_out, int out_size, void* d_ws, size_t ws_size,
                              hipStream_t stream) {
    const float* xyz = (const float*)d_in[0];
    float* out = (float*)d_out;
    float* ws = (float*)d_ws;
    ull* keys = (ull*)d_out;   // scratch: 8.9MB of the 16MB output buffer;
                               // out_kernel overwrites all of it afterwards.

    prep_kernel<<<8, BLKT, 0, stream>>>(xyz, ws);
    knn_kernel<<<1024, BLKT, 0, stream>>>(ws, keys);
    merge_kernel<<<128, 256, 0, stream>>>(ws, keys);
    out_kernel<<<out_size / 1024, 256, 0, stream>>>(xyz, ws, out);
}

// Round 8
// 244.815 us; speedup vs baseline: 1.1943x; 1.1943x over previous
//
#include <hip/hip_runtime.h>
#include <math.h>

// ---------------------------------------------------------------------------
// EncoderGPECls: kNN(16) -> PCA curvature blend -> adaptive GPE embeddings
// xyz: [8,4096,3] f32  ->  out: [8,4096,128] f32
//
// R20 = R19 with the out_kernel grid FIXED back to out_size/1024 (4096
//   blocks). R19's failure was purely the launch line: each out block
//   writes 1024 floats, so out_size/1024 blocks covers the 4,194,304-float
//   output exactly (R18 was correct; R19's "fix" wrote 1/4 and left zeros).
//   knn unchanged from R19 (the actual experiment, still unmeasured):
//   - 2 dispatches: knn (repack+stats folded in, R12-style chunk-0 stats)
//     + lean float4 out_kernel.
//   - Ping-pong copy-free prefetch: pass1 depth-8 (A[8]/B[8], peeled tail),
//     pass2 depth-4. Doubles load-to-use distance (~336 cyc of compute) to
//     cover contended LDS latency; removes 16 v_movs/group.
//   Selection semantics byte-identical to R15's proven path: premultiplied
//   d2' = 3-fma chain (same IEEE ops at every site), sign-flip key encode,
//   exact per-partition tau, SCAP clamp drops latest tie = jax drop, u64
//   (enc,idx) keys = lower-index tie-break, ascending scan order.
//
// ws float layout:
//   [0, 32768)            curv per point
//   [32768, 131072)       rasig2 (3 SoA planes of 32768)
//   [131072, 131584)      curv partial sums [b][chunk] (8 x 64)
//   [131584, 131680)      per-batch raw sums as 48 DOUBLES
// ---------------------------------------------------------------------------

#define NPTS 4096
#define KNN 17          // 16 neighbors + self (self contributes zero to sums)
#define BLKT 512        // 8 waves; 64 queries per block (1 per lane)
#define QPB 64
#define ESIZE 512       // candidates per wave (eighth)
#define SEG 256         // pass-2 segment size (u8 offsets)
#define SCAP 17         // survivor slots per lane per segment

#define WS_CURV  0
#define WS_RAS2  32768
#define WS_CSUM  131072
#define WS_STAT  131584

typedef unsigned long long ull;
#define SENT 0xFFFFFFFFFFFFFFFFULL

// THE single d2' definition: explicit fmaf chain, identical IEEE ops at every
// call site. c = (-2cx,-2cy,-2cz,|c|^2), q = original coords.
// d2'(c,q) = |c|^2 - 2 c.q = |c-q|^2 - |q|^2 (per-query constant offset ->
// identical ordering; can be negative). Self always ranks first.
__device__ __forceinline__ float d2p(float4 c, float qx, float qy, float qz) {
    return __builtin_fmaf(c.x, qx, __builtin_fmaf(c.y, qy,
           __builtin_fmaf(c.z, qz, c.w)));
}

// order-preserving u32 encoding of a (possibly negative) float
__device__ __forceinline__ unsigned encf(float f) {
    unsigned u = __float_as_uint(f);
    return u ^ (unsigned)(((int)u >> 31) | 0x80000000u);
}

// predicated replace-max insert of packed (enc(d2')<<32|idx) key
__device__ __forceinline__ void insertp(ull v, bool ins, ull (&md)[KNN],
                                        ull& maxv, int& maxp) {
#pragma unroll
    for (int k = 0; k < KNN; k++) {
        bool sel = ins && (k == maxp);
        md[k] = sel ? v : md[k];
    }
    maxv = md[0]; maxp = 0;
#pragma unroll
    for (int k = 1; k < KNN; k++) {
        bool g = md[k] > maxv;
        maxv = g ? md[k] : maxv;
        maxp = g ? k : maxp;
    }
}

// ---------------- 3x3 symmetric eigensolve (double, trig method) -----------
__device__ __forceinline__ float curv_from_cov(float c00, float c01, float c02,
                                               float c11, float c12, float c22) {
    double a00 = c00, a01 = c01, a02 = c02, a11 = c11, a12 = c12, a22 = c22;
    double tr = a00 + a11 + a22;
    double q  = tr * (1.0 / 3.0);
    double b00 = a00 - q, b11 = a11 - q, b22 = a22 - q;
    double p2 = b00 * b00 + b11 * b11 + b22 * b22
              + 2.0 * (a01 * a01 + a02 * a02 + a12 * a12);
    double lmin;
    if (p2 < 1e-60) {
        lmin = q;
    } else {
        double p  = sqrt(p2 * (1.0 / 6.0));
        double ip = 1.0 / p;
        double m00 = b00 * ip, m11 = b11 * ip, m22 = b22 * ip;
        double m01 = a01 * ip, m02 = a02 * ip, m12 = a12 * ip;
        double det = m00 * (m11 * m22 - m12 * m12)
                   - m01 * (m01 * m22 - m12 * m02)
                   + m02 * (m01 * m12 - m11 * m02);
        double r = 0.5 * det;
        r = r > 1.0 ? 1.0 : (r < -1.0 ? -1.0 : r);
        double phi = acos(r) * (1.0 / 3.0);
        lmin = q + 2.0 * p * cos(phi + 2.0943951023931953);
    }
    return (float)(lmin / (tr + 1e-6));
}

// ---------------- kNN + covariance + curvature + lstd ----------------------
__global__ __launch_bounds__(BLKT, 4) void knn_kernel(const float* __restrict__ xyz,
                                                      float* __restrict__ ws) {
    __shared__ float4 pts[NPTS];                 // 64 KB premultiplied tile
    __shared__ ull aux[1088];                    // 8704 B arena (aliased)
    unsigned char* sbuf = (unsigned char*)aux;   // [SCAP][BLKT] u8 survivors
    unsigned short* pub = (unsigned short*)aux;  // 4 regions x 64x17 u16 idx
    int b = blockIdx.x >> 6;                     // 64 blocks per batch
    int chunk = blockIdx.x & 63;
    int tid = threadIdx.x;
    const float* base = xyz + b * NPTS * 3;
    for (int p = tid; p < NPTS; p += BLKT) {
        float x = base[p * 3], y = base[p * 3 + 1], z = base[p * 3 + 2];
        float w = __builtin_fmaf(z, z, __builtin_fmaf(y, y, x * x));
        pts[p] = make_float4(-2.0f * x, -2.0f * y, -2.0f * z, w);
    }
    __syncthreads();

    // ---- chunk-0 block computes per-batch raw sums in double (into aux) ----
    if (chunk == 0) {
        double sx = 0, sy = 0, sz = 0, qxx = 0, qyy = 0, qzz = 0;
        for (int p = tid; p < NPTS; p += BLKT) {
            float4 c = pts[p];
            float x = -0.5f * c.x, y = -0.5f * c.y, z = -0.5f * c.z; // exact
            sx += (double)x; sy += (double)y; sz += (double)z;
            qxx += (double)x * x; qyy += (double)y * y; qzz += (double)z * z;
        }
        for (int off = 32; off > 0; off >>= 1) {
            sx += __shfl_down(sx, off);  sy += __shfl_down(sy, off);
            sz += __shfl_down(sz, off);  qxx += __shfl_down(qxx, off);
            qyy += __shfl_down(qyy, off); qzz += __shfl_down(qzz, off);
        }
        double* dstat = (double*)aux;
        int wid = tid >> 6;
        if ((tid & 63) == 0) {
            dstat[wid * 6 + 0] = sx;  dstat[wid * 6 + 1] = sy;  dstat[wid * 6 + 2] = sz;
            dstat[wid * 6 + 3] = qxx; dstat[wid * 6 + 4] = qyy; dstat[wid * 6 + 5] = qzz;
        }
        __syncthreads();
        if (tid == 0) {
            double* wd = (double*)(ws + WS_STAT);
            for (int qq = 0; qq < 6; qq++) {
                double a = 0.0;
                for (int w = 0; w < 8; w++) a += dstat[w * 6 + qq];
                wd[b * 6 + qq] = a;
            }
        }
        __syncthreads();                         // aux free for survivor use
    }

    int wv = tid >> 6;                           // wave id: candidate eighth
    int lane = tid & 63;
    int i = chunk * QPB + lane;                  // this lane's query point
    float4 qc = pts[i];
    float qx = -0.5f * qc.x, qy = -0.5f * qc.y, qz = -0.5f * qc.z;  // exact
    int cbase = wv * ESIZE;                      // this wave's candidate range

    // ---- pass 1: med3 top-17 ladder, depth-8 copy-free ping-pong ----------
    float md[KNN];
#pragma unroll
    for (int k = 0; k < KNN; k++) md[k] = 3.4e38f;

#define LADDER(c) { \
    float d2 = d2p((c), qx, qy, qz); \
    _Pragma("unroll") \
    for (int k = KNN - 1; k >= 1; k--) \
        md[k] = __builtin_amdgcn_fmed3f(d2, md[k - 1], md[k]); \
    md[0] = fminf(d2, md[0]); }

    {
        float4 A[8], B[8];
#pragma unroll
        for (int u = 0; u < 8; u++) A[u] = pts[cbase + u];
        for (int m = 0; m < ESIZE - 16; m += 16) {
#pragma unroll
            for (int u = 0; u < 8; u++) B[u] = pts[cbase + m + 8 + u];
#pragma unroll
            for (int u = 0; u < 8; u++) LADDER(A[u]);
#pragma unroll
            for (int u = 0; u < 8; u++) A[u] = pts[cbase + m + 16 + u];
#pragma unroll
            for (int u = 0; u < 8; u++) LADDER(B[u]);
        }
        // tail: A = [ESIZE-16, ESIZE-8)
#pragma unroll
        for (int u = 0; u < 8; u++) B[u] = pts[cbase + ESIZE - 8 + u];
#pragma unroll
        for (int u = 0; u < 8; u++) LADDER(A[u]);
#pragma unroll
        for (int u = 0; u < 8; u++) LADDER(B[u]);
    }
#undef LADDER
    float tau = md[KNN - 1];   // exact 17th (identical fmaf chain everywhere)

    // ---- pass 2 (2 segments of 256): u8 survivors, depth-4 ping-pong ------
    ull k17[KNN];
#pragma unroll
    for (int k = 0; k < KNN; k++) k17[k] = SENT;
    ull maxv = SENT; int maxp = 0;

#define P2BODY(c, off) { \
    float d2 = d2p((c), qx, qy, qz); \
    if (d2 <= tau) {                    /* clamp drops latest tie = jax */ \
        if (cnt < SCAP) sbuf[cnt * BLKT + tid] = (unsigned char)(off); \
        cnt++; } }

#pragma unroll
    for (int sgi = 0; sgi < 2; sgi++) {
        int segbase = cbase + sgi * SEG;
        int cnt = 0;
        {
            float4 A[4], B[4];
#pragma unroll
            for (int u = 0; u < 4; u++) A[u] = pts[segbase + u];
            for (int m = 0; m < SEG - 8; m += 8) {
#pragma unroll
                for (int u = 0; u < 4; u++) B[u] = pts[segbase + m + 4 + u];
#pragma unroll
                for (int u = 0; u < 4; u++) P2BODY(A[u], m + u);
#pragma unroll
                for (int u = 0; u < 4; u++) A[u] = pts[segbase + m + 8 + u];
#pragma unroll
                for (int u = 0; u < 4; u++) P2BODY(B[u], m + 4 + u);
            }
#pragma unroll
            for (int u = 0; u < 4; u++) B[u] = pts[segbase + SEG - 4 + u];
#pragma unroll
            for (int u = 0; u < 4; u++) P2BODY(A[u], SEG - 8 + u);
#pragma unroll
            for (int u = 0; u < 4; u++) P2BODY(B[u], SEG - 4 + u);
        }
        // drain this segment's survivors into the exact u64 top-17
#pragma unroll
        for (int t = 0; t < SCAP; t++) {
            if (__any(t < cnt)) {
                int ix = segbase + sbuf[t * BLKT + tid];
                float4 c = pts[ix];
                float d2 = d2p(c, qx, qy, qz);
                ull key = ((ull)encf(d2) << 32) | (unsigned)ix;
                bool ins = (t < cnt) && (key < maxv);
                if (__any(ins)) insertp(key, ins, k17, maxv, maxp);
            }
        }
    }
#undef P2BODY

    // ---- 3-round tournament merge (u16 idx publish, keys rebuilt exactly) --
    // regions: r * 1088 u16 entries, entry lane*17+k
    __syncthreads();
    if (wv & 1) {
#pragma unroll
        for (int k = 0; k < KNN; k++)
            pub[(wv >> 1) * 1088 + lane * KNN + k] = (unsigned short)(k17[k] & 0xffffULL);
    }
    __syncthreads();
    if (!(wv & 1)) {
        int r = wv >> 1;
#pragma unroll
        for (int k = 0; k < KNN; k++) {
            int ix = pub[r * 1088 + lane * KNN + k];
            float4 c = pts[ix];
            float d2 = d2p(c, qx, qy, qz);
            ull key = ((ull)encf(d2) << 32) | (unsigned)ix;
            bool ins = key < maxv;
            if (__any(ins)) insertp(key, ins, k17, maxv, maxp);
        }
    }
    // round 2: 2->0, 6->4 (regions 0,1)
    __syncthreads();
    if (wv == 2 || wv == 6) {
#pragma unroll
        for (int k = 0; k < KNN; k++)
            pub[(wv >> 2) * 1088 + lane * KNN + k] = (unsigned short)(k17[k] & 0xffffULL);
    }
    __syncthreads();
    if (wv == 0 || wv == 4) {
        int r = wv >> 2;
#pragma unroll
        for (int k = 0; k < KNN; k++) {
            int ix = pub[r * 1088 + lane * KNN + k];
            float4 c = pts[ix];
            float d2 = d2p(c, qx, qy, qz);
            ull key = ((ull)encf(d2) << 32) | (unsigned)ix;
            bool ins = key < maxv;
            if (__any(ins)) insertp(key, ins, k17, maxv, maxp);
        }
    }
    // round 3: 4->0 (region 0)
    __syncthreads();
    if (wv == 4) {
#pragma unroll
        for (int k = 0; k < KNN; k++)
            pub[lane * KNN + k] = (unsigned short)(k17[k] & 0xffffULL);
    }
    __syncthreads();

    // ---- epilogue on wave 0: final merge + moments -> curv, rasig2 --------
    if (wv == 0) {
#pragma unroll
        for (int k = 0; k < KNN; k++) {
            int ix = pub[lane * KNN + k];
            float4 c = pts[ix];
            float d2 = d2p(c, qx, qy, qz);
            ull key = ((ull)encf(d2) << 32) | (unsigned)ix;
            bool ins = key < maxv;
            if (__any(ins)) insertp(key, ins, k17, maxv, maxp);
        }

        float s1x = 0, s1y = 0, s1z = 0;
        float cxx = 0, cxy = 0, cxz = 0, cyy = 0, cyz = 0, czz = 0;
#pragma unroll
        for (int k = 0; k < KNN; k++) {
            int j = (int)(k17[k] & 0xffffffffULL);
            float4 c = pts[j];
            float ux = -0.5f * c.x - qx;         // exact original coords
            float uy = -0.5f * c.y - qy;
            float uz = -0.5f * c.z - qz;
            s1x += ux; s1y += uy; s1z += uz;
            cxx += ux * ux; cxy += ux * uy; cxz += ux * uz;
            cyy += uy * uy; cyz += uy * uz; czz += uz * uz;
        }
        const float i16 = 1.0f / 16.0f, i15 = 1.0f / 15.0f;
        float mx = s1x * i16, my = s1y * i16, mz = s1z * i16;
        float c00 = (cxx - 16.0f * mx * mx) * i15;
        float c01 = (cxy - 16.0f * mx * my) * i15;
        float c02 = (cxz - 16.0f * mx * mz) * i15;
        float c11 = (cyy - 16.0f * my * my) * i15;
        float c12 = (cyz - 16.0f * my * mz) * i15;
        float c22 = (czz - 16.0f * mz * mz) * i15;

        float curv = curv_from_cov(c00, c01, c02, c11, c12, c22);

        float v0 = c00 > 0.0f ? c00 : 0.0f;
        float v1 = c11 > 0.0f ? c11 : 0.0f;
        float v2 = c22 > 0.0f ? c22 : 0.0f;
        float r2x = 1.0f / (0.3f * (1.0f + sqrtf(v0)) + 1e-6f);
        float r2y = 1.0f / (0.3f * (1.0f + sqrtf(v1)) + 1e-6f);
        float r2z = 1.0f / (0.3f * (1.0f + sqrtf(v2)) + 1e-6f);

        int g = b * NPTS + i;
        ws[WS_CURV + g] = curv;
        ws[WS_RAS2 + 0 * 32768 + g] = r2x;
        ws[WS_RAS2 + 1 * 32768 + g] = r2y;
        ws[WS_RAS2 + 2 * 32768 + g] = r2z;

        // non-atomic per-(b,chunk) partial sum
        float cs = curv;
        for (int off = 32; off > 0; off >>= 1) cs += __shfl_down(cs, off);
        if (lane == 0) ws[WS_CSUM + b * 64 + chunk] = cs;
    }
}

// ---------------- final embedding (lean prefix, float4 stores) -------------
__global__ void out_kernel(const float* __restrict__ xyz,
                           const float* __restrict__ ws,
                           float* __restrict__ out) {
    __shared__ float sc[3];                      // rasig1, blend, 1-blend
    __shared__ float scm[8];                     // per-batch curv mean
    if (threadIdx.x < 64) {
        // gstd from double stats (24 lanes) -> sigmoid scalars
        float part = 0.0f;
        if (threadIdx.x < 24) {
            const double* st = (const double*)(ws + WS_STAT);
            int bb = threadIdx.x / 3, dd = threadIdx.x % 3;
            double s = st[bb * 6 + dd], ss = st[bb * 6 + 3 + dd];
            double var = (ss - s * s / 4096.0) / 4095.0;
            part = (float)sqrt(var > 0.0 ? var : 0.0);
        }
        float p2 = part;
        for (int off = 32; off > 0; off >>= 1) p2 += __shfl_down(p2, off);
        if (threadIdx.x == 0) {
            float gf = p2 * (1.0f / 24.0f);
            float denom = 0.3f * (1.0f + gf) + 1e-6f;
            float blend = 1.0f / (1.0f + __expf(-(gf - 0.1f) * 10.0f));
            sc[0] = 1.0f / denom;
            sc[1] = blend;
            sc[2] = 1.0f - blend;
        }
        // per-batch curv means from 512 partials: lane L sums [L*8, L*8+8)
        float cp = 0.0f;
        const float* pf = ws + WS_CSUM;
#pragma unroll
        for (int t = 0; t < 8; t++) cp += pf[threadIdx.x * 8 + t];
        cp += __shfl_down(cp, 4);
        cp += __shfl_down(cp, 2);
        cp += __shfl_down(cp, 1);
        if ((threadIdx.x & 7) == 0) scm[threadIdx.x >> 3] = cp * (1.0f / 4096.0f);
    }
    __syncthreads();

    int q4 = blockIdx.x * 256 + (int)threadIdx.x;     // quad id (4 outputs)
    int j0 = (q4 & 31) << 2;                          // 32 quads per point
    int g  = q4 >> 5;
    int b  = g >> 12;
    float rasig1 = sc[0];
    float blend  = sc[1];
    float blendc = sc[2];
    float curv   = ws[WS_CURV + g];
    float w = 1.0f / (1.0f + __expf(-10.0f * (curv - scm[b])));
    float wc = 1.0f - w;

    float o[4];
#pragma unroll
    for (int e = 0; e < 4; e++) {
        int j = j0 + e;
        int f = (j < 127) ? j : 128;                  // OUT_IDX
        int d = (f >= 86) ? 2 : ((f >= 43) ? 1 : 0);
        int t = f - d * 43;
        float fv = (float)((double)(t + 1) * (2.0 / 44.0) - 1.0);  // FEAT_VAL
        float x = xyz[g * 3 + d];
        float t1 = (x - fv) * rasig1;
        float e1 = blend * __expf(-0.5f * t1 * t1) + blendc * __cosf(t1);
        float t2 = (x - fv) * ws[WS_RAS2 + (d << 15) + g];
        float e2 = __expf(-0.5f * t2 * t2);
        o[e] = w * e1 + wc * e2;
    }
    *(float4*)(out + ((long)q4 << 2)) = make_float4(o[0], o[1], o[2], o[3]);
}

extern "C" void kernel_launch(void* const* d_in, const int* in_sizes, int n_in,
                              void* d_out, int out_size, void* d_ws, size_t ws_size,
                              hipStream_t stream) {
    const float* xyz = (const float*)d_in[0];
    float* out = (float*)d_out;
    float* ws = (float*)d_ws;

    knn_kernel<<<512, BLKT, 0, stream>>>(xyz, ws);
    // each block writes 256 threads x 4 floats = 1024 floats
    out_kernel<<<out_size / 1024, 256, 0, stream>>>(xyz, ws, out);
}